// Round 9
// baseline (265.283 us; speedup 1.0000x reference)
//
#include <hip/hip_runtime.h>
#include <stdint.h>

// ---------- types / helpers ----------
typedef __attribute__((ext_vector_type(8))) short short8;   // 8 x bf16 bits
typedef __attribute__((ext_vector_type(4))) float f32x4;

__device__ __forceinline__ unsigned short f2bf(float f) {
  unsigned u = __float_as_uint(f);
  u += 0x7fffu + ((u >> 16) & 1u);           // round-to-nearest-even
  return (unsigned short)(u >> 16);
}
__device__ __forceinline__ float bf2f(unsigned short u) {
  return __uint_as_float(((unsigned)u) << 16);
}

#define GLDS16(gp, lp)                                              \
  __builtin_amdgcn_global_load_lds(                                  \
      (const __attribute__((address_space(1))) void*)(gp),           \
      (__attribute__((address_space(3))) void*)(lp), 16, 0, 0)

// ---------- kernel 1: cast h (f32) -> hA (bf16) ----------
__global__ void __launch_bounds__(256) cast_h_kernel(const float* __restrict__ h,
                                                     unsigned short* __restrict__ hA,
                                                     long long total8) {
  long long i = (long long)blockIdx.x * 256 + threadIdx.x;
  if (i >= total8) return;
  const float4* p = (const float4*)(h + i * 8);
  float4 f0 = p[0], f1 = p[1];
  short8 r;
  r[0] = (short)f2bf(f0.x); r[1] = (short)f2bf(f0.y);
  r[2] = (short)f2bf(f0.z); r[3] = (short)f2bf(f0.w);
  r[4] = (short)f2bf(f1.x); r[5] = (short)f2bf(f1.y);
  r[6] = (short)f2bf(f1.z); r[7] = (short)f2bf(f1.w);
  *(short8*)(hA + i * 8) = r;
}

// ---------- kernel 2: BT[n][k] = bf16(W1[(n>=512? 512:0)+k][n&511]) ----------
__global__ void __launch_bounds__(256) buildBT_kernel(const float* __restrict__ W1,
                                                      unsigned short* __restrict__ BT) {
  int t = blockIdx.x * 256 + threadIdx.x;   // 0..524287
  int n = t >> 9;
  int k = t & 511;
  float v = W1[((size_t)((n >> 9) * 512 + k)) * 512 + (size_t)(n & 511)];
  BT[t] = f2bf(v);
}

// ---------- kernel 3: GEMM  P[M][1024](bf16) = hA[M][512] @ BT^T (+b1 cols<512) ----------
// OCCUPANCY VARIANT: 128x64 tile, BK=64, 256 threads (4 waves as 2x2, each 64x32,
// acc[4][2]=32 f32) -> ~105 total regs < 128-step => 16 waves/CU (2x prior).
// 24 KB LDS. Proven 2-barrier schedule, XOR swizzle, repack epilogue.
__global__ void __launch_bounds__(256, 4) gemm_kernel(const unsigned short* __restrict__ hA,
                                                      const unsigned short* __restrict__ BT,
                                                      const float* __restrict__ b1,
                                                      unsigned short* __restrict__ P,
                                                      int M) {
  __shared__ unsigned short As[128 * 64];   // 16 KB
  __shared__ unsigned short Bs[64 * 64];    // 8 KB

  // --- XCD-chunked block swizzle; logical order: n-tile fastest within an A strip ---
  const int nwg = gridDim.x;                // Mtiles*16, divisible by 8
  const int cpx = nwg >> 3;
  const int wg  = (blockIdx.x & 7) * cpx + (blockIdx.x >> 3);
  const int nt  = wg & 15;
  const int mt  = wg >> 4;
  const int m0  = mt * 128;
  const int n0  = nt * 64;

  const int tid  = threadIdx.x;
  const int lane = tid & 63;
  const int wid  = tid >> 6;
  const int wr   = wid >> 1, wc = wid & 1;   // wave = rows [wr*64,+64) x cols [wc*32,+32)
  const int lr   = lane & 15;
  const int g    = lane >> 4;                // 0..3

  f32x4 acc[4][2];
#pragma unroll
  for (int i = 0; i < 4; ++i)
#pragma unroll
    for (int j = 0; j < 2; ++j) acc[i][j] = (f32x4){0.f, 0.f, 0.f, 0.f};

  const int srow = tid >> 3;     // 0..31 (q adds +32)
  const int slot = tid & 7;      // 16B slot within 128B row

#pragma unroll 1
  for (int kt = 0; kt < 8; ++kt) {
    const int k0 = kt * 64;
    // stage A: 128 rows (4 chunks/thread)
#pragma unroll
    for (int q = 0; q < 4; ++q) {
      const int row = q * 32 + srow;
      const int gk  = k0 + ((slot ^ (row & 7)) << 3);
      const int ga  = m0 + row;
      if (ga < M) GLDS16(hA + (size_t)ga * 512 + gk, &As[row * 64 + slot * 8]);
    }
    // stage B: 64 rows (2 chunks/thread)
#pragma unroll
    for (int q = 0; q < 2; ++q) {
      const int row = q * 32 + srow;
      const int gk  = k0 + ((slot ^ (row & 7)) << 3);
      GLDS16(BT + (size_t)(n0 + row) * 512 + gk, &Bs[row * 64 + slot * 8]);
    }
    __syncthreads();   // drains vmcnt: tiles staged

    short8 aF[2][4], bF[2][2];
#pragma unroll
    for (int s = 0; s < 2; ++s) {
#pragma unroll
      for (int i = 0; i < 4; ++i) {
        const int row = wr * 64 + i * 16 + lr;
        const int p   = (s * 4 + g) ^ (row & 7);
        aF[s][i] = *(const short8*)&As[row * 64 + p * 8];
      }
#pragma unroll
      for (int j = 0; j < 2; ++j) {
        const int row = wc * 32 + j * 16 + lr;
        const int p   = (s * 4 + g) ^ (row & 7);
        bF[s][j] = *(const short8*)&Bs[row * 64 + p * 8];
      }
    }
#pragma unroll
    for (int s = 0; s < 2; ++s)
#pragma unroll
      for (int i = 0; i < 4; ++i)
#pragma unroll
        for (int j = 0; j < 2; ++j)
          acc[i][j] = __builtin_amdgcn_mfma_f32_16x16x32_bf16(aF[s][i], bF[s][j], acc[i][j], 0, 0, 0);
    __syncthreads();   // all reads done before next stage overwrites
  }

  // --- epilogue: bias + bf16 + LDS repack for coalesced stores ---
  float bias[2];
#pragma unroll
  for (int j = 0; j < 2; ++j) {
    const int col = n0 + wc * 32 + j * 16 + lr;
    bias[j] = (col < 512) ? b1[col] : 0.0f;
  }
  unsigned short* Ls = As;               // 32 x 64 bf16 = 4 KB, reuse
  const int rowL = tid >> 3;             // 0..31
  const int c0   = (tid & 7) * 8;        // 8 elems = 16B per thread
  const int grS  = m0 + (rowL >> 4) * 64 + (rowL & 15);   // +i*16 per pass
#pragma unroll
  for (int i = 0; i < 4; ++i) {
    // wave (wr,wc) rows: m0 + wr*64 + i*16 + g*4+r ; cols: n0 + wc*32 + j*16 + lr
#pragma unroll
    for (int j = 0; j < 2; ++j) {
      const int col  = wc * 32 + j * 16 + lr;
      const int lrow = wr * 16 + g * 4;
#pragma unroll
      for (int r = 0; r < 4; ++r)
        Ls[(lrow + r) * 64 + col] = f2bf(acc[i][j][r] + bias[j]);
    }
    __syncthreads();
    const int gr = grS + i * 16;
    if (gr < M) {
      const short8 v = *(const short8*)&Ls[rowL * 64 + c0];
      *(short8*)(P + (size_t)gr * 1024 + n0 + c0) = v;
    }
    __syncthreads();
  }
}

// ---------- kernel 4: per-edge score ----------
__global__ void __launch_bounds__(256) edge_kernel(const unsigned short* __restrict__ P,
                                                   const int* __restrict__ src,
                                                   const int* __restrict__ dst,
                                                   const float* __restrict__ W2,
                                                   const float* __restrict__ b2,
                                                   float* __restrict__ out,
                                                   int E) {
  const int gw   = (blockIdx.x * 256 + threadIdx.x) >> 6;   // global wave = edge
  const int lane = threadIdx.x & 63;
  if (gw >= E) return;
  const int s = src[gw];
  const int d = dst[gw];
  const short8 va = *(const short8*)(P + (size_t)s * 1024 + lane * 8);
  const short8 vb = *(const short8*)(P + (size_t)d * 1024 + 512 + lane * 8);
  const float4 w0 = *(const float4*)(W2 + lane * 8);
  const float4 w1 = *(const float4*)(W2 + lane * 8 + 4);
  float a = 0.f, x;
  x = bf2f((unsigned short)va[0]) + bf2f((unsigned short)vb[0]); a += fmaxf(x, 0.f) * w0.x;
  x = bf2f((unsigned short)va[1]) + bf2f((unsigned short)vb[1]); a += fmaxf(x, 0.f) * w0.y;
  x = bf2f((unsigned short)va[2]) + bf2f((unsigned short)vb[2]); a += fmaxf(x, 0.f) * w0.z;
  x = bf2f((unsigned short)va[3]) + bf2f((unsigned short)vb[3]); a += fmaxf(x, 0.f) * w0.w;
  x = bf2f((unsigned short)va[4]) + bf2f((unsigned short)vb[4]); a += fmaxf(x, 0.f) * w1.x;
  x = bf2f((unsigned short)va[5]) + bf2f((unsigned short)vb[5]); a += fmaxf(x, 0.f) * w1.y;
  x = bf2f((unsigned short)va[6]) + bf2f((unsigned short)vb[6]); a += fmaxf(x, 0.f) * w1.z;
  x = bf2f((unsigned short)va[7]) + bf2f((unsigned short)vb[7]); a += fmaxf(x, 0.f) * w1.w;
#pragma unroll
  for (int o = 32; o > 0; o >>= 1) a += __shfl_down(a, o);
  if (lane == 0) out[gw] = a + b2[0];
}

// ---------- launcher ----------
extern "C" void kernel_launch(void* const* d_in, const int* in_sizes, int n_in,
                              void* d_out, int out_size, void* d_ws, size_t ws_size,
                              hipStream_t stream) {
  const float* h  = (const float*)d_in[0];
  const int*   src = (const int*)d_in[1];
  const int*   dst = (const int*)d_in[2];
  const float* W1 = (const float*)d_in[3];
  const float* b1 = (const float*)d_in[4];
  const float* W2 = (const float*)d_in[5];
  const float* b2 = (const float*)d_in[6];
  float* out = (float*)d_out;

  const int M = in_sizes[0] / 512;   // 100000 nodes
  const int E = in_sizes[1];         // 160000 edges

  char* ws = (char*)d_ws;
  unsigned short* hA = (unsigned short*)ws;                          // M*512 bf16
  size_t off = (((size_t)M * 512 * 2) + 255) & ~(size_t)255;
  unsigned short* BT = (unsigned short*)(ws + off);                  // 1024*512 bf16
  off += (size_t)1024 * 512 * 2;
  unsigned short* P = (unsigned short*)(ws + off);                   // M*1024 bf16

  const long long total8 = (long long)M * 512 / 8;
  cast_h_kernel<<<(int)((total8 + 255) / 256), 256, 0, stream>>>(h, hA, total8);
  buildBT_kernel<<<2048, 256, 0, stream>>>(W1, BT);
  const int Mtiles = (M + 127) / 128;          // 782
  gemm_kernel<<<Mtiles * 16, 256, 0, stream>>>(hA, BT, b1, P, M);
  edge_kernel<<<(E + 3) / 4, 256, 0, stream>>>(P, src, dst, W2, b2, out, E);
}